// Round 14
// baseline (246.983 us; speedup 1.0000x reference)
//
#include <hip/hip_runtime.h>
#include <hip/hip_bf16.h>

#define CIN  128
#define COUT 128
#define BN_EPS 1e-5f
#define RPB   64           // rows per bucket (power of 2)
#define MAXNB 2048         // max buckets (N <= 131072)
#define PCHUNK 8192        // edges per partition block
#define CAP   2560         // padded capacity per bucket (mean 2046 + 11 sigma)
#define GB    512          // gemm blocks in fused kernel
#define LDP   136          // padded LDS row stride (shorts): 272B, 16B-divisible

typedef __attribute__((ext_vector_type(8))) short short8;
typedef __attribute__((ext_vector_type(4))) float f32x4;

// round-to-nearest-even f32 -> bf16 bits
__device__ __forceinline__ unsigned short f2bf(float f) {
    unsigned u = __float_as_uint(f);
    u += 0x7fffu + ((u >> 16) & 1u);
    return (unsigned short)(u >> 16);
}

// ---------------------------------------------------------------------------
// GEMM body: Z_theta[N,128] = Z_H[N,128] @ W[128,128] + b  (bf16 out, MFMA)
// Persistent over 64-row tiles; W fragments held in VGPRs.
// Epilogue: acc -> padded LDS -> coalesced uint4 (8-short) stores.
// Fragment layout (16x16x32): A/B lane l: m|n = l&15, k = (l>>4)*8 + e.
// C/D (verified): col = l&15, row = (l>>4)*4 + reg.
// ---------------------------------------------------------------------------
__device__ __forceinline__ void gemm_body(
    const float* __restrict__ Z, const float* __restrict__ W,
    const float* __restrict__ b, unsigned short* __restrict__ Zt,
    int N, int bid)
{
    __shared__ unsigned short cls[64 * LDP];   // 17.4 KB C-tile bounce buffer

    const int t    = threadIdx.x;
    const int lane = t & 63;
    const int wid  = t >> 6;
    const int lm   = lane & 15;
    const int lg   = lane >> 4;

    short8 bfr[4][8];
#pragma unroll
    for (int kc = 0; kc < 4; ++kc) {
#pragma unroll
        for (int ct = 0; ct < 8; ++ct) {
            union { short8 v; unsigned short u[8]; } bf;
#pragma unroll
            for (int e = 0; e < 8; ++e)
                bf.u[e] = f2bf(W[(kc * 32 + lg * 8 + e) * COUT + ct * 16 + lm]);
            bfr[kc][ct] = bf.v;
        }
    }

    float bias[8];
#pragma unroll
    for (int ct = 0; ct < 8; ++ct) bias[ct] = b[ct * 16 + lm];

    const int tr = t >> 4;      // epilogue row 0..15
    const int cc = t & 15;      // epilogue 8-short chunk 0..15

    const int ntiles = (N + 63) / 64;
    for (int tile = bid; tile < ntiles; tile += GB) {
        const int row0 = tile * 64 + wid * 16;
        const int arow = row0 + lm;
        const bool aval = arow < N;
        const float* zrow = Z + (size_t)arow * CIN;

        f32x4 acc[8];
#pragma unroll
        for (int ct = 0; ct < 8; ++ct) {
            f32x4 a = {bias[ct], bias[ct], bias[ct], bias[ct]};
            acc[ct] = a;
        }

#pragma unroll
        for (int kc = 0; kc < 4; ++kc) {
            union { short8 v; unsigned short u[8]; } af;
            if (aval) {
                const float4 z0 = *((const float4*)(zrow + kc * 32 + lg * 8));
                const float4 z1 = *((const float4*)(zrow + kc * 32 + lg * 8 + 4));
                af.u[0] = f2bf(z0.x); af.u[1] = f2bf(z0.y);
                af.u[2] = f2bf(z0.z); af.u[3] = f2bf(z0.w);
                af.u[4] = f2bf(z1.x); af.u[5] = f2bf(z1.y);
                af.u[6] = f2bf(z1.z); af.u[7] = f2bf(z1.w);
            } else {
#pragma unroll
                for (int e = 0; e < 8; ++e) af.u[e] = 0;
            }
#pragma unroll
            for (int ct = 0; ct < 8; ++ct)
                acc[ct] = __builtin_amdgcn_mfma_f32_16x16x32_bf16(
                    af.v, bfr[kc][ct], acc[ct], 0, 0, 0);
        }

        // epilogue: acc -> LDS -> coalesced 16B stores
        __syncthreads();   // previous tile's LDS readers done
#pragma unroll
        for (int i = 0; i < 4; ++i) {
            const int r = wid * 16 + lg * 4 + i;
#pragma unroll
            for (int ct = 0; ct < 8; ++ct)
                cls[r * LDP + ct * 16 + lm] = f2bf(acc[ct][i]);
        }
        __syncthreads();

#pragma unroll
        for (int j = 0; j < 4; ++j) {
            const int r = j * 16 + tr;
            const int grow = tile * 64 + r;
            if (grow < N) {
                const uint4 v = *((const uint4*)&cls[r * LDP + cc * 8]);
                *((uint4*)(Zt + (size_t)grow * COUT + cc * 8)) = v;
            }
        }
    }
}

// ---------------------------------------------------------------------------
// Partition body: bucket edges into PADDED per-bucket regions.
// bucketCur holds RELATIVE offsets (zero-init); absolute = b*CAP + rel.
// Payload: col (17b) | row-local (6b) << 17, val.
// ---------------------------------------------------------------------------
__device__ __forceinline__ void partition_body(
    const int* __restrict__ rows, const int* __restrict__ cols,
    const float* __restrict__ vals, int* __restrict__ bucketCur,
    uint2* __restrict__ ebuck, int nnz, int NB, int pb)
{
    __shared__ int h[MAXNB];
    __shared__ int basecur[MAXNB];
    const int t = threadIdx.x;

    for (int i = t; i < NB; i += 256) h[i] = 0;
    __syncthreads();

    const int c0 = pb * PCHUNK;
    const int ce = min(c0 + PCHUNK, nnz);

    int rloc[PCHUNK / 256];
#pragma unroll
    for (int j = 0; j < PCHUNK / 256; ++j) {
        const int i = c0 + j * 256 + t;
        int r = -1;
        if (i < ce) r = rows[i];
        rloc[j] = r;
        if (r >= 0) atomicAdd(&h[r >> 6], 1);
    }
    __syncthreads();

    for (int i = t; i < NB; i += 256) {
        const int c = h[i];
        basecur[i] = c ? (i * CAP + atomicAdd(&bucketCur[i], c)) : 0;
    }
    __syncthreads();

#pragma unroll
    for (int j = 0; j < PCHUNK / 256; ++j) {
        const int i = c0 + j * 256 + t;
        const int r = rloc[j];
        if (r >= 0) {
            const int p = atomicAdd(&basecur[r >> 6], 1);
            ebuck[p] = make_uint2((unsigned)cols[i] | ((unsigned)(r & (RPB - 1)) << 17),
                                  __float_as_uint(vals[i]));
        }
    }
}

// ---------------------------------------------------------------------------
// Kernel 1: fused partition (blocks 0..pblocks-1) || GEMM (rest).
// Partition blocks FIRST so they run in the shadow of the longer GEMM.
// ---------------------------------------------------------------------------
__global__ __launch_bounds__(256, 2) void gemm_part_kernel(
    const float* __restrict__ Z, const float* __restrict__ W,
    const float* __restrict__ b, unsigned short* __restrict__ Zt,
    const int* __restrict__ rows, const int* __restrict__ cols,
    const float* __restrict__ vals, int* __restrict__ bucketCur,
    uint2* __restrict__ ebuck, int nnz, int N, int NB, int pblocks)
{
    if ((int)blockIdx.x < pblocks) {
        partition_body(rows, cols, vals, bucketCur, ebuck, nnz, NB, blockIdx.x);
    } else {
        gemm_body(Z, W, b, Zt, N, blockIdx.x - pblocks);
    }
}

// ---------------------------------------------------------------------------
// Kernel 2: fused per-bucket row-sort (in LDS) + per-row gather + BN stats.
// One block per bucket. Edges loaded once (register stage, static indexing),
// LDS 64-bin count+scan+scatter -> sorted buffer, then 8B/lane
// register-accumulate gather (descriptors broadcast from LDS).
// ---------------------------------------------------------------------------
__global__ __launch_bounds__(256) void gather_build_kernel(
    const unsigned short* __restrict__ Zt, const uint2* __restrict__ ebuck,
    const int* __restrict__ bucketCur, unsigned int* __restrict__ Zc,
    float* __restrict__ stats, int N)
{
    __shared__ int cnt[RPB];
    __shared__ int scn[RPB];
    __shared__ int loc[RPB];
    __shared__ uint2 ebuf[CAP];        // 20 KB sorted edges
    __shared__ float sbuf[256];

    const int t = threadIdx.x;
    const int b = blockIdx.x;
    const int base = b * CAP;
    int count = bucketCur[b];
    if (count > CAP) count = CAP;

    sbuf[t] = 0.f;
    if (t < RPB) cnt[t] = 0;
    __syncthreads();

    uint2 er[CAP / 256];
#pragma unroll
    for (int j = 0; j < CAP / 256; ++j) {
        const int i = j * 256 + t;
        if (i < count) {
            er[j] = ebuck[base + i];
            atomicAdd(&cnt[er[j].x >> 17], 1);
        }
    }
    __syncthreads();

    if (t < RPB) scn[t] = cnt[t];
    __syncthreads();
#pragma unroll
    for (int off = 1; off < RPB; off <<= 1) {
        int v = 0;
        if (t < RPB && t >= off) v = scn[t - off];
        __syncthreads();
        if (t < RPB) scn[t] += v;
        __syncthreads();
    }
    if (t < RPB) loc[t] = scn[t] - cnt[t];
    __syncthreads();

#pragma unroll
    for (int j = 0; j < CAP / 256; ++j) {
        const int i = j * 256 + t;
        if (i < count) {
            const uint2 e = er[j];
            const int rl  = (int)(e.x >> 17);
            const int pos = atomicAdd(&loc[rl], 1);
            ebuf[pos] = make_uint2(e.x & 0x1FFFFu, e.y);
        }
    }
    __syncthreads();

    const int wid  = t >> 6;
    const int lane = t & 63;
    const int eo   = lane >> 5;
    const int cg   = lane & 31;

    float s0 = 0.f, s1 = 0.f, s2 = 0.f, s3 = 0.f;
    float q0 = 0.f, q1 = 0.f, q2 = 0.f, q3 = 0.f;

    const int row0 = b * RPB;
    for (int r = wid; r < RPB; r += 4) {
        const int row = row0 + r;
        if (row >= N) break;
        const int end = scn[r];
        const int beg = end - cnt[r];

        float a0 = 0.f, a1 = 0.f, a2 = 0.f, a3 = 0.f;

        int i = beg + eo;
        for (; i + 6 < end; i += 8) {
            const uint2 p0 = ebuf[i];
            const uint2 p1 = ebuf[i + 2];
            const uint2 p2 = ebuf[i + 4];
            const uint2 p3 = ebuf[i + 6];
            const uint2 g0 = *((const uint2*)(Zt + (size_t)p0.x * COUT + cg * 4));
            const uint2 g1 = *((const uint2*)(Zt + (size_t)p1.x * COUT + cg * 4));
            const uint2 g2 = *((const uint2*)(Zt + (size_t)p2.x * COUT + cg * 4));
            const uint2 g3 = *((const uint2*)(Zt + (size_t)p3.x * COUT + cg * 4));
            const float v0 = __uint_as_float(p0.y);
            const float v1 = __uint_as_float(p1.y);
            const float v2 = __uint_as_float(p2.y);
            const float v3 = __uint_as_float(p3.y);
            a0 = fmaf(v0, __uint_as_float(g0.x << 16), a0);
            a1 = fmaf(v0, __uint_as_float(g0.x & 0xffff0000u), a1);
            a2 = fmaf(v0, __uint_as_float(g0.y << 16), a2);
            a3 = fmaf(v0, __uint_as_float(g0.y & 0xffff0000u), a3);
            a0 = fmaf(v1, __uint_as_float(g1.x << 16), a0);
            a1 = fmaf(v1, __uint_as_float(g1.x & 0xffff0000u), a1);
            a2 = fmaf(v1, __uint_as_float(g1.y << 16), a2);
            a3 = fmaf(v1, __uint_as_float(g1.y & 0xffff0000u), a3);
            a0 = fmaf(v2, __uint_as_float(g2.x << 16), a0);
            a1 = fmaf(v2, __uint_as_float(g2.x & 0xffff0000u), a1);
            a2 = fmaf(v2, __uint_as_float(g2.y << 16), a2);
            a3 = fmaf(v2, __uint_as_float(g2.y & 0xffff0000u), a3);
            a0 = fmaf(v3, __uint_as_float(g3.x << 16), a0);
            a1 = fmaf(v3, __uint_as_float(g3.x & 0xffff0000u), a1);
            a2 = fmaf(v3, __uint_as_float(g3.y << 16), a2);
            a3 = fmaf(v3, __uint_as_float(g3.y & 0xffff0000u), a3);
        }
        for (; i < end; i += 2) {
            const uint2 p = ebuf[i];
            const uint2 g = *((const uint2*)(Zt + (size_t)p.x * COUT + cg * 4));
            const float vp = __uint_as_float(p.y);
            a0 = fmaf(vp, __uint_as_float(g.x << 16), a0);
            a1 = fmaf(vp, __uint_as_float(g.x & 0xffff0000u), a1);
            a2 = fmaf(vp, __uint_as_float(g.y << 16), a2);
            a3 = fmaf(vp, __uint_as_float(g.y & 0xffff0000u), a3);
        }

        a0 += __shfl_xor(a0, 32);
        a1 += __shfl_xor(a1, 32);
        a2 += __shfl_xor(a2, 32);
        a3 += __shfl_xor(a3, 32);

        if (eo == 0) {
            uint2 o;
            o.x = (unsigned)f2bf(a0) | ((unsigned)f2bf(a1) << 16);
            o.y = (unsigned)f2bf(a2) | ((unsigned)f2bf(a3) << 16);
            *((uint2*)(Zc + (size_t)row * (COUT / 2) + cg * 2)) = o;
            s0 += a0; s1 += a1; s2 += a2; s3 += a3;
            q0 = fmaf(a0, a0, q0);
            q1 = fmaf(a1, a1, q1);
            q2 = fmaf(a2, a2, q2);
            q3 = fmaf(a3, a3, q3);
        }
    }

    if (eo == 0) {
        const int c0 = cg * 4;
        atomicAdd(&sbuf[c0 + 0], s0);
        atomicAdd(&sbuf[c0 + 1], s1);
        atomicAdd(&sbuf[c0 + 2], s2);
        atomicAdd(&sbuf[c0 + 3], s3);
        atomicAdd(&sbuf[128 + c0 + 0], q0);
        atomicAdd(&sbuf[128 + c0 + 1], q1);
        atomicAdd(&sbuf[128 + c0 + 2], q2);
        atomicAdd(&sbuf[128 + c0 + 3], q3);
    }
    __syncthreads();
    atomicAdd(&stats[t], sbuf[t]);
}

// ---------------------------------------------------------------------------
// Kernel 3: BN(normalize) + ReLU + row-max -> out[N]  (bf16 Zc input)
// ---------------------------------------------------------------------------
__global__ __launch_bounds__(256) void finalize_kernel(
    const unsigned int* __restrict__ Zc, const float* __restrict__ stats,
    const float* __restrict__ gamma, const float* __restrict__ beta,
    float* __restrict__ out, int N)
{
    const int row = blockIdx.x * 4 + (threadIdx.x >> 6);
    if (row >= N) return;
    const int lane = threadIdx.x & 63;
    const int c0 = lane * 2;

    const unsigned g = Zc[(size_t)row * (COUT / 2) + lane];
    const float x0 = __uint_as_float(g << 16);
    const float x1 = __uint_as_float(g & 0xffff0000u);

    const float invN = 1.0f / (float)N;
    const float m0 = stats[c0] * invN;
    const float m1 = stats[c0 + 1] * invN;
    const float v0 = stats[128 + c0] * invN - m0 * m0;
    const float v1 = stats[128 + c0 + 1] * invN - m1 * m1;
    const float sc0 = gamma[c0]     * rsqrtf(v0 + BN_EPS);
    const float sc1 = gamma[c0 + 1] * rsqrtf(v1 + BN_EPS);

    float y0 = (x0 - m0) * sc0 + beta[c0];
    float y1 = (x1 - m1) * sc1 + beta[c0 + 1];
    y0 = fmaxf(y0, 0.f);
    y1 = fmaxf(y1, 0.f);

    float mx = fmaxf(y0, y1);
#pragma unroll
    for (int off = 32; off > 0; off >>= 1)
        mx = fmaxf(mx, __shfl_xor(mx, off));

    if (lane == 0) out[row] = mx;
}

// ---------------------------------------------------------------------------
extern "C" void kernel_launch(void* const* d_in, const int* in_sizes, int n_in,
                              void* d_out, int out_size, void* d_ws, size_t ws_size,
                              hipStream_t stream)
{
    const float* Z_H   = (const float*)d_in[0];
    const float* vals  = (const float*)d_in[1];
    const float* W     = (const float*)d_in[2];
    const float* b     = (const float*)d_in[3];
    const float* gamma = (const float*)d_in[4];
    const float* beta  = (const float*)d_in[5];
    const int*   rows  = (const int*)d_in[6];
    const int*   cols  = (const int*)d_in[7];
    float* out = (float*)d_out;

    const int N   = in_sizes[0] / CIN;
    const int nnz = in_sizes[1];
    const int NB  = (N + RPB - 1) / RPB;
    const int pblocks = (nnz + PCHUNK - 1) / PCHUNK;

    // workspace layout (bucketCur and stats adjacent -> single memset)
    char* ws = (char*)d_ws;
    size_t off = 0;
    unsigned short* Zt = (unsigned short*)(ws + off); off += (size_t)N * COUT * sizeof(unsigned short);
    unsigned int*   Zc = (unsigned int*)(ws + off);   off += (size_t)N * (COUT / 2) * sizeof(unsigned int);
    uint2* ebuck  = (uint2*)(ws + off);  off += (size_t)NB * CAP * sizeof(uint2);
    int* bucketCur = (int*)(ws + off);   off += (size_t)NB * sizeof(int);
    float* stats   = (float*)(ws + off); off += 256 * sizeof(float);

    hipMemsetAsync(bucketCur, 0, ((size_t)NB + 256) * sizeof(int), stream);

    // 1) fused: bucket partition (first) || persistent MFMA GEMM
    gemm_part_kernel<<<pblocks + GB, 256, 0, stream>>>(
        Z_H, W, b, Zt, rows, cols, vals, bucketCur, ebuck, nnz, N, NB, pblocks);

    // 2) fused per-bucket sort + gather + BN stats
    gather_build_kernel<<<NB, 256, 0, stream>>>(Zt, ebuck, bucketCur, Zc, stats, N);

    // 3) BN + ReLU + rowmax
    finalize_kernel<<<(N + 3) / 4, 256, 0, stream>>>(Zc, stats, gamma, beta, out, N);
}

// Round 15
// 242.857 us; speedup vs baseline: 1.0170x; 1.0170x over previous
//
#include <hip/hip_runtime.h>
#include <hip/hip_bf16.h>

#define CIN  128
#define COUT 128
#define BN_EPS 1e-5f
#define RPB   64           // rows per bucket (power of 2)
#define MAXNB 2048         // max buckets (N <= 131072)
#define PCHUNK 8192        // edges per partition block
#define CAP   2560         // padded capacity per bucket (mean 2046 + 11 sigma)
#define LDP   136          // padded LDS row stride (shorts): 272B, 16B-divisible

typedef __attribute__((ext_vector_type(8))) short short8;
typedef __attribute__((ext_vector_type(4))) float f32x4;

// packed f32x2 -> bf16x2 bits (compiler lowers to v_cvt_pk_bf16_f32)
__device__ __forceinline__ unsigned pk2bf(float lo, float hi) {
    union { __hip_bfloat162 h; unsigned u; } c;
    c.h = __float22bfloat162_rn(make_float2(lo, hi));
    return c.u;
}

// scalar f32 -> bf16 bits (RNE)
__device__ __forceinline__ unsigned short f2bf(float f) {
    unsigned u = __float_as_uint(f);
    u += 0x7fffu + ((u >> 16) & 1u);
    return (unsigned short)(u >> 16);
}

// ---------------------------------------------------------------------------
// GEMM body: Z_theta[N,128] = Z_H[N,128] @ W[128,128] + b  (bf16 out, MFMA)
// Persistent over 64-row tiles; W fragments held in VGPRs; packed bf16
// conversion everywhere (v_cvt_pk_bf16_f32).
// Fragment layout (16x16x32): A/B lane l: m|n = l&15, k = (l>>4)*8 + e.
// C/D (verified): col = l&15, row = (l>>4)*4 + reg.
// ---------------------------------------------------------------------------
__device__ __forceinline__ void gemm_body(
    const float* __restrict__ Z, const float* __restrict__ W,
    const float* __restrict__ b, unsigned short* __restrict__ Zt,
    int N, int bid, int gb)
{
    __shared__ unsigned short cls[64 * LDP];   // 17.4 KB C-tile bounce buffer

    const int t    = threadIdx.x;
    const int lane = t & 63;
    const int wid  = t >> 6;
    const int lm   = lane & 15;
    const int lg   = lane >> 4;

    short8 bfr[4][8];
#pragma unroll
    for (int kc = 0; kc < 4; ++kc) {
#pragma unroll
        for (int ct = 0; ct < 8; ++ct) {
            union { short8 v; unsigned u32[4]; } bf;
#pragma unroll
            for (int e = 0; e < 8; e += 2) {
                const float w0 = W[(kc * 32 + lg * 8 + e)     * COUT + ct * 16 + lm];
                const float w1 = W[(kc * 32 + lg * 8 + e + 1) * COUT + ct * 16 + lm];
                bf.u32[e >> 1] = pk2bf(w0, w1);
            }
            bfr[kc][ct] = bf.v;
        }
    }

    float bias[8];
#pragma unroll
    for (int ct = 0; ct < 8; ++ct) bias[ct] = b[ct * 16 + lm];

    const int tr = t >> 4;      // epilogue row 0..15
    const int cc = t & 15;      // epilogue 8-short chunk 0..15

    const int ntiles = (N + 63) / 64;
    for (int tile = bid; tile < ntiles; tile += gb) {
        const int row0 = tile * 64 + wid * 16;
        const int arow = row0 + lm;
        const bool aval = arow < N;
        const float* zrow = Z + (size_t)arow * CIN;

        f32x4 acc[8];
#pragma unroll
        for (int ct = 0; ct < 8; ++ct) {
            f32x4 a = {bias[ct], bias[ct], bias[ct], bias[ct]};
            acc[ct] = a;
        }

#pragma unroll
        for (int kc = 0; kc < 4; ++kc) {
            union { short8 v; unsigned u32[4]; } af;
            if (aval) {
                const float4 z0 = *((const float4*)(zrow + kc * 32 + lg * 8));
                const float4 z1 = *((const float4*)(zrow + kc * 32 + lg * 8 + 4));
                af.u32[0] = pk2bf(z0.x, z0.y);
                af.u32[1] = pk2bf(z0.z, z0.w);
                af.u32[2] = pk2bf(z1.x, z1.y);
                af.u32[3] = pk2bf(z1.z, z1.w);
            } else {
#pragma unroll
                for (int e = 0; e < 4; ++e) af.u32[e] = 0;
            }
#pragma unroll
            for (int ct = 0; ct < 8; ++ct)
                acc[ct] = __builtin_amdgcn_mfma_f32_16x16x32_bf16(
                    af.v, bfr[kc][ct], acc[ct], 0, 0, 0);
        }

        // epilogue: acc -> LDS (packed converts) -> coalesced 16B stores
        __syncthreads();   // previous tile's LDS readers done
#pragma unroll
        for (int i = 0; i < 4; ++i) {
            const int r = wid * 16 + lg * 4 + i;
#pragma unroll
            for (int ct = 0; ct < 8; ct += 2) {
                const unsigned u = pk2bf(acc[ct][i], acc[ct + 1][i]);
                cls[r * LDP + ct * 16 + lm]       = (unsigned short)(u & 0xffffu);
                cls[r * LDP + (ct + 1) * 16 + lm] = (unsigned short)(u >> 16);
            }
        }
        __syncthreads();

#pragma unroll
        for (int j = 0; j < 4; ++j) {
            const int r = j * 16 + tr;
            const int grow = tile * 64 + r;
            if (grow < N) {
                const uint4 v = *((const uint4*)&cls[r * LDP + cc * 8]);
                *((uint4*)(Zt + (size_t)grow * COUT + cc * 8)) = v;
            }
        }
    }
}

// ---------------------------------------------------------------------------
// Partition body: bucket edges into PADDED per-bucket regions.
// bucketCur holds RELATIVE offsets (zero-init); absolute = b*CAP + rel.
// Payload: col (17b) | row-local (6b) << 17, val.
// ---------------------------------------------------------------------------
__device__ __forceinline__ void partition_body(
    const int* __restrict__ rows, const int* __restrict__ cols,
    const float* __restrict__ vals, int* __restrict__ bucketCur,
    uint2* __restrict__ ebuck, int nnz, int NB, int pb)
{
    __shared__ int h[MAXNB];
    __shared__ int basecur[MAXNB];
    const int t = threadIdx.x;

    for (int i = t; i < NB; i += 256) h[i] = 0;
    __syncthreads();

    const int c0 = pb * PCHUNK;
    const int ce = min(c0 + PCHUNK, nnz);

    int rloc[PCHUNK / 256];
#pragma unroll
    for (int j = 0; j < PCHUNK / 256; ++j) {
        const int i = c0 + j * 256 + t;
        int r = -1;
        if (i < ce) r = rows[i];
        rloc[j] = r;
        if (r >= 0) atomicAdd(&h[r >> 6], 1);
    }
    __syncthreads();

    for (int i = t; i < NB; i += 256) {
        const int c = h[i];
        basecur[i] = c ? (i * CAP + atomicAdd(&bucketCur[i], c)) : 0;
    }
    __syncthreads();

#pragma unroll
    for (int j = 0; j < PCHUNK / 256; ++j) {
        const int i = c0 + j * 256 + t;
        const int r = rloc[j];
        if (r >= 0) {
            const int p = atomicAdd(&basecur[r >> 6], 1);
            ebuck[p] = make_uint2((unsigned)cols[i] | ((unsigned)(r & (RPB - 1)) << 17),
                                  __float_as_uint(vals[i]));
        }
    }
}

// ---------------------------------------------------------------------------
// Kernel 1: fused partition (blocks 0..pblocks-1) || GEMM (rest).
// Partition blocks FIRST so they run in the shadow of the longer GEMM.
// gb chosen on host so every GEMM block does exactly ceil(ntiles/gb)=3 tiles.
// ---------------------------------------------------------------------------
__global__ __launch_bounds__(256, 2) void gemm_part_kernel(
    const float* __restrict__ Z, const float* __restrict__ W,
    const float* __restrict__ b, unsigned short* __restrict__ Zt,
    const int* __restrict__ rows, const int* __restrict__ cols,
    const float* __restrict__ vals, int* __restrict__ bucketCur,
    uint2* __restrict__ ebuck, int nnz, int N, int NB, int pblocks, int gb)
{
    if ((int)blockIdx.x < pblocks) {
        partition_body(rows, cols, vals, bucketCur, ebuck, nnz, NB, blockIdx.x);
    } else {
        gemm_body(Z, W, b, Zt, N, blockIdx.x - pblocks, gb);
    }
}

// ---------------------------------------------------------------------------
// Kernel 2: fused per-bucket row-sort (in LDS) + per-row gather + BN stats.
// One block per bucket. Edges loaded once (register stage, static indexing),
// LDS 64-bin count+scan+scatter -> sorted buffer, then 8B/lane
// register-accumulate gather (descriptors broadcast from LDS).
// ---------------------------------------------------------------------------
__global__ __launch_bounds__(256) void gather_build_kernel(
    const unsigned short* __restrict__ Zt, const uint2* __restrict__ ebuck,
    const int* __restrict__ bucketCur, unsigned int* __restrict__ Zc,
    float* __restrict__ stats, int N)
{
    __shared__ int cnt[RPB];
    __shared__ int scn[RPB];
    __shared__ int loc[RPB];
    __shared__ uint2 ebuf[CAP];        // 20 KB sorted edges
    __shared__ float sbuf[256];

    const int t = threadIdx.x;
    const int b = blockIdx.x;
    const int base = b * CAP;
    int count = bucketCur[b];
    if (count > CAP) count = CAP;

    sbuf[t] = 0.f;
    if (t < RPB) cnt[t] = 0;
    __syncthreads();

    uint2 er[CAP / 256];
#pragma unroll
    for (int j = 0; j < CAP / 256; ++j) {
        const int i = j * 256 + t;
        if (i < count) {
            er[j] = ebuck[base + i];
            atomicAdd(&cnt[er[j].x >> 17], 1);
        }
    }
    __syncthreads();

    if (t < RPB) scn[t] = cnt[t];
    __syncthreads();
#pragma unroll
    for (int off = 1; off < RPB; off <<= 1) {
        int v = 0;
        if (t < RPB && t >= off) v = scn[t - off];
        __syncthreads();
        if (t < RPB) scn[t] += v;
        __syncthreads();
    }
    if (t < RPB) loc[t] = scn[t] - cnt[t];
    __syncthreads();

#pragma unroll
    for (int j = 0; j < CAP / 256; ++j) {
        const int i = j * 256 + t;
        if (i < count) {
            const uint2 e = er[j];
            const int rl  = (int)(e.x >> 17);
            const int pos = atomicAdd(&loc[rl], 1);
            ebuf[pos] = make_uint2(e.x & 0x1FFFFu, e.y);
        }
    }
    __syncthreads();

    const int wid  = t >> 6;
    const int lane = t & 63;
    const int eo   = lane >> 5;
    const int cg   = lane & 31;

    float s0 = 0.f, s1 = 0.f, s2 = 0.f, s3 = 0.f;
    float q0 = 0.f, q1 = 0.f, q2 = 0.f, q3 = 0.f;

    const int row0 = b * RPB;
    for (int r = wid; r < RPB; r += 4) {
        const int row = row0 + r;
        if (row >= N) break;
        const int end = scn[r];
        const int beg = end - cnt[r];

        float a0 = 0.f, a1 = 0.f, a2 = 0.f, a3 = 0.f;

        int i = beg + eo;
        for (; i + 6 < end; i += 8) {
            const uint2 p0 = ebuf[i];
            const uint2 p1 = ebuf[i + 2];
            const uint2 p2 = ebuf[i + 4];
            const uint2 p3 = ebuf[i + 6];
            const uint2 g0 = *((const uint2*)(Zt + (size_t)p0.x * COUT + cg * 4));
            const uint2 g1 = *((const uint2*)(Zt + (size_t)p1.x * COUT + cg * 4));
            const uint2 g2 = *((const uint2*)(Zt + (size_t)p2.x * COUT + cg * 4));
            const uint2 g3 = *((const uint2*)(Zt + (size_t)p3.x * COUT + cg * 4));
            const float v0 = __uint_as_float(p0.y);
            const float v1 = __uint_as_float(p1.y);
            const float v2 = __uint_as_float(p2.y);
            const float v3 = __uint_as_float(p3.y);
            a0 = fmaf(v0, __uint_as_float(g0.x << 16), a0);
            a1 = fmaf(v0, __uint_as_float(g0.x & 0xffff0000u), a1);
            a2 = fmaf(v0, __uint_as_float(g0.y << 16), a2);
            a3 = fmaf(v0, __uint_as_float(g0.y & 0xffff0000u), a3);
            a0 = fmaf(v1, __uint_as_float(g1.x << 16), a0);
            a1 = fmaf(v1, __uint_as_float(g1.x & 0xffff0000u), a1);
            a2 = fmaf(v1, __uint_as_float(g1.y << 16), a2);
            a3 = fmaf(v1, __uint_as_float(g1.y & 0xffff0000u), a3);
            a0 = fmaf(v2, __uint_as_float(g2.x << 16), a0);
            a1 = fmaf(v2, __uint_as_float(g2.x & 0xffff0000u), a1);
            a2 = fmaf(v2, __uint_as_float(g2.y << 16), a2);
            a3 = fmaf(v2, __uint_as_float(g2.y & 0xffff0000u), a3);
            a0 = fmaf(v3, __uint_as_float(g3.x << 16), a0);
            a1 = fmaf(v3, __uint_as_float(g3.x & 0xffff0000u), a1);
            a2 = fmaf(v3, __uint_as_float(g3.y << 16), a2);
            a3 = fmaf(v3, __uint_as_float(g3.y & 0xffff0000u), a3);
        }
        for (; i < end; i += 2) {
            const uint2 p = ebuf[i];
            const uint2 g = *((const uint2*)(Zt + (size_t)p.x * COUT + cg * 4));
            const float vp = __uint_as_float(p.y);
            a0 = fmaf(vp, __uint_as_float(g.x << 16), a0);
            a1 = fmaf(vp, __uint_as_float(g.x & 0xffff0000u), a1);
            a2 = fmaf(vp, __uint_as_float(g.y << 16), a2);
            a3 = fmaf(vp, __uint_as_float(g.y & 0xffff0000u), a3);
        }

        a0 += __shfl_xor(a0, 32);
        a1 += __shfl_xor(a1, 32);
        a2 += __shfl_xor(a2, 32);
        a3 += __shfl_xor(a3, 32);

        if (eo == 0) {
            uint2 o;
            o.x = pk2bf(a0, a1);
            o.y = pk2bf(a2, a3);
            *((uint2*)(Zc + (size_t)row * (COUT / 2) + cg * 2)) = o;
            s0 += a0; s1 += a1; s2 += a2; s3 += a3;
            q0 = fmaf(a0, a0, q0);
            q1 = fmaf(a1, a1, q1);
            q2 = fmaf(a2, a2, q2);
            q3 = fmaf(a3, a3, q3);
        }
    }

    if (eo == 0) {
        const int c0 = cg * 4;
        atomicAdd(&sbuf[c0 + 0], s0);
        atomicAdd(&sbuf[c0 + 1], s1);
        atomicAdd(&sbuf[c0 + 2], s2);
        atomicAdd(&sbuf[c0 + 3], s3);
        atomicAdd(&sbuf[128 + c0 + 0], q0);
        atomicAdd(&sbuf[128 + c0 + 1], q1);
        atomicAdd(&sbuf[128 + c0 + 2], q2);
        atomicAdd(&sbuf[128 + c0 + 3], q3);
    }
    __syncthreads();
    atomicAdd(&stats[t], sbuf[t]);
}

// ---------------------------------------------------------------------------
// Kernel 3: BN(normalize) + ReLU + row-max -> out[N]  (bf16 Zc input)
// ---------------------------------------------------------------------------
__global__ __launch_bounds__(256) void finalize_kernel(
    const unsigned int* __restrict__ Zc, const float* __restrict__ stats,
    const float* __restrict__ gamma, const float* __restrict__ beta,
    float* __restrict__ out, int N)
{
    const int row = blockIdx.x * 4 + (threadIdx.x >> 6);
    if (row >= N) return;
    const int lane = threadIdx.x & 63;
    const int c0 = lane * 2;

    const unsigned g = Zc[(size_t)row * (COUT / 2) + lane];
    const float x0 = __uint_as_float(g << 16);
    const float x1 = __uint_as_float(g & 0xffff0000u);

    const float invN = 1.0f / (float)N;
    const float m0 = stats[c0] * invN;
    const float m1 = stats[c0 + 1] * invN;
    const float v0 = stats[128 + c0] * invN - m0 * m0;
    const float v1 = stats[128 + c0 + 1] * invN - m1 * m1;
    const float sc0 = gamma[c0]     * rsqrtf(v0 + BN_EPS);
    const float sc1 = gamma[c0 + 1] * rsqrtf(v1 + BN_EPS);

    float y0 = (x0 - m0) * sc0 + beta[c0];
    float y1 = (x1 - m1) * sc1 + beta[c0 + 1];
    y0 = fmaxf(y0, 0.f);
    y1 = fmaxf(y1, 0.f);

    float mx = fmaxf(y0, y1);
#pragma unroll
    for (int off = 32; off > 0; off >>= 1)
        mx = fmaxf(mx, __shfl_xor(mx, off));

    if (lane == 0) out[row] = mx;
}

// ---------------------------------------------------------------------------
extern "C" void kernel_launch(void* const* d_in, const int* in_sizes, int n_in,
                              void* d_out, int out_size, void* d_ws, size_t ws_size,
                              hipStream_t stream)
{
    const float* Z_H   = (const float*)d_in[0];
    const float* vals  = (const float*)d_in[1];
    const float* W     = (const float*)d_in[2];
    const float* b     = (const float*)d_in[3];
    const float* gamma = (const float*)d_in[4];
    const float* beta  = (const float*)d_in[5];
    const int*   rows  = (const int*)d_in[6];
    const int*   cols  = (const int*)d_in[7];
    float* out = (float*)d_out;

    const int N   = in_sizes[0] / CIN;
    const int nnz = in_sizes[1];
    const int NB  = (N + RPB - 1) / RPB;
    const int pblocks = (nnz + PCHUNK - 1) / PCHUNK;
    const int ntiles  = (N + 63) / 64;
    const int gb      = (ntiles + 2) / 3;    // exactly 3 tiles per gemm block

    // workspace layout (bucketCur and stats adjacent -> single memset)
    char* ws = (char*)d_ws;
    size_t off = 0;
    unsigned short* Zt = (unsigned short*)(ws + off); off += (size_t)N * COUT * sizeof(unsigned short);
    unsigned int*   Zc = (unsigned int*)(ws + off);   off += (size_t)N * (COUT / 2) * sizeof(unsigned int);
    uint2* ebuck  = (uint2*)(ws + off);  off += (size_t)NB * CAP * sizeof(uint2);
    int* bucketCur = (int*)(ws + off);   off += (size_t)NB * sizeof(int);
    float* stats   = (float*)(ws + off); off += 256 * sizeof(float);

    hipMemsetAsync(bucketCur, 0, ((size_t)NB + 256) * sizeof(int), stream);

    // 1) fused: bucket partition (first) || persistent MFMA GEMM
    gemm_part_kernel<<<pblocks + gb, 256, 0, stream>>>(
        Z_H, W, b, Zt, rows, cols, vals, bucketCur, ebuck, nnz, N, NB, pblocks, gb);

    // 2) fused per-bucket sort + gather + BN stats
    gather_build_kernel<<<NB, 256, 0, stream>>>(Zt, ebuck, bucketCur, Zc, stats, N);

    // 3) BN + ReLU + rowmax
    finalize_kernel<<<(N + 3) / 4, 256, 0, stream>>>(Zc, stats, gamma, beta, out, N);
}

// Round 16
// 232.747 us; speedup vs baseline: 1.0612x; 1.0434x over previous
//
#include <hip/hip_runtime.h>
#include <hip/hip_bf16.h>

#define CIN  128
#define COUT 128
#define BN_EPS 1e-5f
#define RPB   64           // rows per bucket (power of 2)
#define MAXNB 2048         // max buckets (N <= 131072)
#define PCHUNK 8192        // edges per partition block
#define CAP   2560         // padded capacity per bucket (mean 2046 + 11 sigma)
#define LDP   136          // padded LDS row stride (shorts): 272B, 16B-divisible

typedef __attribute__((ext_vector_type(8))) short short8;
typedef __attribute__((ext_vector_type(4))) float f32x4;

// packed f32x2 -> bf16x2 bits (compiler lowers to v_cvt_pk_bf16_f32)
__device__ __forceinline__ unsigned pk2bf(float lo, float hi) {
    union { __hip_bfloat162 h; unsigned u; } c;
    c.h = __float22bfloat162_rn(make_float2(lo, hi));
    return c.u;
}

// ---------------------------------------------------------------------------
// GEMM body: Z_theta[N,128] = Z_H[N,128] @ W[128,128] + b  (bf16 out, MFMA)
// Persistent over 64-row tiles; W fragments held in VGPRs; packed bf16
// conversion everywhere (v_cvt_pk_bf16_f32).
// Fragment layout (16x16x32): A/B lane l: m|n = l&15, k = (l>>4)*8 + e.
// C/D (verified): col = l&15, row = (l>>4)*4 + reg.
// ---------------------------------------------------------------------------
__device__ __forceinline__ void gemm_body(
    const float* __restrict__ Z, const float* __restrict__ W,
    const float* __restrict__ b, unsigned short* __restrict__ Zt,
    int N, int bid, int gb)
{
    __shared__ unsigned short cls[64 * LDP];   // 17.4 KB C-tile bounce buffer

    const int t    = threadIdx.x;
    const int lane = t & 63;
    const int wid  = t >> 6;
    const int lm   = lane & 15;
    const int lg   = lane >> 4;

    short8 bfr[4][8];
#pragma unroll
    for (int kc = 0; kc < 4; ++kc) {
#pragma unroll
        for (int ct = 0; ct < 8; ++ct) {
            union { short8 v; unsigned u32[4]; } bf;
#pragma unroll
            for (int e = 0; e < 8; e += 2) {
                const float w0 = W[(kc * 32 + lg * 8 + e)     * COUT + ct * 16 + lm];
                const float w1 = W[(kc * 32 + lg * 8 + e + 1) * COUT + ct * 16 + lm];
                bf.u32[e >> 1] = pk2bf(w0, w1);
            }
            bfr[kc][ct] = bf.v;
        }
    }

    float bias[8];
#pragma unroll
    for (int ct = 0; ct < 8; ++ct) bias[ct] = b[ct * 16 + lm];

    const int tr = t >> 4;      // epilogue row 0..15
    const int cc = t & 15;      // epilogue 8-short chunk 0..15

    const int ntiles = (N + 63) / 64;
    for (int tile = bid; tile < ntiles; tile += gb) {
        const int row0 = tile * 64 + wid * 16;
        const int arow = row0 + lm;
        const bool aval = arow < N;
        const float* zrow = Z + (size_t)arow * CIN;

        f32x4 acc[8];
#pragma unroll
        for (int ct = 0; ct < 8; ++ct) {
            f32x4 a = {bias[ct], bias[ct], bias[ct], bias[ct]};
            acc[ct] = a;
        }

#pragma unroll
        for (int kc = 0; kc < 4; ++kc) {
            union { short8 v; unsigned u32[4]; } af;
            if (aval) {
                const float4 z0 = *((const float4*)(zrow + kc * 32 + lg * 8));
                const float4 z1 = *((const float4*)(zrow + kc * 32 + lg * 8 + 4));
                af.u32[0] = pk2bf(z0.x, z0.y);
                af.u32[1] = pk2bf(z0.z, z0.w);
                af.u32[2] = pk2bf(z1.x, z1.y);
                af.u32[3] = pk2bf(z1.z, z1.w);
            } else {
#pragma unroll
                for (int e = 0; e < 4; ++e) af.u32[e] = 0;
            }
#pragma unroll
            for (int ct = 0; ct < 8; ++ct)
                acc[ct] = __builtin_amdgcn_mfma_f32_16x16x32_bf16(
                    af.v, bfr[kc][ct], acc[ct], 0, 0, 0);
        }

        // epilogue: acc -> LDS (packed converts) -> coalesced 16B stores
        __syncthreads();   // previous tile's LDS readers done
#pragma unroll
        for (int i = 0; i < 4; ++i) {
            const int r = wid * 16 + lg * 4 + i;
#pragma unroll
            for (int ct = 0; ct < 8; ct += 2) {
                const unsigned u = pk2bf(acc[ct][i], acc[ct + 1][i]);
                cls[r * LDP + ct * 16 + lm]       = (unsigned short)(u & 0xffffu);
                cls[r * LDP + (ct + 1) * 16 + lm] = (unsigned short)(u >> 16);
            }
        }
        __syncthreads();

#pragma unroll
        for (int j = 0; j < 4; ++j) {
            const int r = j * 16 + tr;
            const int grow = tile * 64 + r;
            if (grow < N) {
                const uint4 v = *((const uint4*)&cls[r * LDP + cc * 8]);
                *((uint4*)(Zt + (size_t)grow * COUT + cc * 8)) = v;
            }
        }
    }
}

// ---------------------------------------------------------------------------
// Partition body: bucket edges into PADDED per-bucket regions.
// bucketCur holds RELATIVE offsets (zero-init); absolute = b*CAP + rel.
// Payload: col (17b) | row-local (6b) << 17, val.
// ---------------------------------------------------------------------------
__device__ __forceinline__ void partition_body(
    const int* __restrict__ rows, const int* __restrict__ cols,
    const float* __restrict__ vals, int* __restrict__ bucketCur,
    uint2* __restrict__ ebuck, int nnz, int NB, int pb)
{
    __shared__ int h[MAXNB];
    __shared__ int basecur[MAXNB];
    const int t = threadIdx.x;

    for (int i = t; i < NB; i += 256) h[i] = 0;
    __syncthreads();

    const int c0 = pb * PCHUNK;
    const int ce = min(c0 + PCHUNK, nnz);

    int rloc[PCHUNK / 256];
#pragma unroll
    for (int j = 0; j < PCHUNK / 256; ++j) {
        const int i = c0 + j * 256 + t;
        int r = -1;
        if (i < ce) r = rows[i];
        rloc[j] = r;
        if (r >= 0) atomicAdd(&h[r >> 6], 1);
    }
    __syncthreads();

    for (int i = t; i < NB; i += 256) {
        const int c = h[i];
        basecur[i] = c ? (i * CAP + atomicAdd(&bucketCur[i], c)) : 0;
    }
    __syncthreads();

#pragma unroll
    for (int j = 0; j < PCHUNK / 256; ++j) {
        const int i = c0 + j * 256 + t;
        const int r = rloc[j];
        if (r >= 0) {
            const int p = atomicAdd(&basecur[r >> 6], 1);
            ebuck[p] = make_uint2((unsigned)cols[i] | ((unsigned)(r & (RPB - 1)) << 17),
                                  __float_as_uint(vals[i]));
        }
    }
}

// ---------------------------------------------------------------------------
// Kernel 1: fused partition (blocks 0..pblocks-1) || GEMM (rest).
// ---------------------------------------------------------------------------
__global__ __launch_bounds__(256, 2) void gemm_part_kernel(
    const float* __restrict__ Z, const float* __restrict__ W,
    const float* __restrict__ b, unsigned short* __restrict__ Zt,
    const int* __restrict__ rows, const int* __restrict__ cols,
    const float* __restrict__ vals, int* __restrict__ bucketCur,
    uint2* __restrict__ ebuck, int nnz, int N, int NB, int pblocks, int gb)
{
    if ((int)blockIdx.x < pblocks) {
        partition_body(rows, cols, vals, bucketCur, ebuck, nnz, NB, blockIdx.x);
    } else {
        gemm_body(Z, W, b, Zt, N, blockIdx.x - pblocks, gb);
    }
}

// ---------------------------------------------------------------------------
// Kernel 2: fused per-bucket row-sort (in LDS) + CHANNEL-SPLIT two-pass
// per-row gather + BN stats. Pass p covers channels [p*64, p*64+64): the
// per-pass Zt working set is 12.8 MB (half), raising L2 hit rate on the
// random col reads. Sorted ebuf stays in LDS across both passes.
// ---------------------------------------------------------------------------
__global__ __launch_bounds__(256) void gather_build_kernel(
    const unsigned short* __restrict__ Zt, const uint2* __restrict__ ebuck,
    const int* __restrict__ bucketCur, unsigned int* __restrict__ Zc,
    float* __restrict__ stats, int N)
{
    __shared__ int cnt[RPB];
    __shared__ int scn[RPB];
    __shared__ int loc[RPB];
    __shared__ uint2 ebuf[CAP];        // 20 KB sorted edges
    __shared__ float sbuf[256];

    const int t = threadIdx.x;
    const int b = blockIdx.x;
    const int base = b * CAP;
    int count = bucketCur[b];
    if (count > CAP) count = CAP;

    sbuf[t] = 0.f;
    if (t < RPB) cnt[t] = 0;
    __syncthreads();

    uint2 er[CAP / 256];
#pragma unroll
    for (int j = 0; j < CAP / 256; ++j) {
        const int i = j * 256 + t;
        if (i < count) {
            er[j] = ebuck[base + i];
            atomicAdd(&cnt[er[j].x >> 17], 1);
        }
    }
    __syncthreads();

    if (t < RPB) scn[t] = cnt[t];
    __syncthreads();
#pragma unroll
    for (int off = 1; off < RPB; off <<= 1) {
        int v = 0;
        if (t < RPB && t >= off) v = scn[t - off];
        __syncthreads();
        if (t < RPB) scn[t] += v;
        __syncthreads();
    }
    if (t < RPB) loc[t] = scn[t] - cnt[t];
    __syncthreads();

#pragma unroll
    for (int j = 0; j < CAP / 256; ++j) {
        const int i = j * 256 + t;
        if (i < count) {
            const uint2 e = er[j];
            const int rl  = (int)(e.x >> 17);
            const int pos = atomicAdd(&loc[rl], 1);
            ebuf[pos] = make_uint2(e.x & 0x1FFFFu, e.y);
        }
    }
    __syncthreads();

    const int wid  = t >> 6;
    const int lane = t & 63;
    const int eo   = lane >> 5;
    const int cg   = lane & 31;

    const int row0 = b * RPB;

#pragma unroll
    for (int pass = 0; pass < 2; ++pass) {
        const int choff = pass * 64 + cg * 2;   // this lane's channel pair

        float s0 = 0.f, s1 = 0.f, q0 = 0.f, q1 = 0.f;

        for (int r = wid; r < RPB; r += 4) {
            const int row = row0 + r;
            if (row >= N) break;
            const int end = scn[r];
            const int beg = end - cnt[r];

            float a0 = 0.f, a1 = 0.f;

            int i = beg + eo;
            // 4 pair-steps per iter -> 8 edges in flight per wave
            for (; i + 6 < end; i += 8) {
                const uint2 p0 = ebuf[i];
                const uint2 p1 = ebuf[i + 2];
                const uint2 p2 = ebuf[i + 4];
                const uint2 p3 = ebuf[i + 6];
                const unsigned g0 = *((const unsigned*)(Zt + (size_t)p0.x * COUT + choff));
                const unsigned g1 = *((const unsigned*)(Zt + (size_t)p1.x * COUT + choff));
                const unsigned g2 = *((const unsigned*)(Zt + (size_t)p2.x * COUT + choff));
                const unsigned g3 = *((const unsigned*)(Zt + (size_t)p3.x * COUT + choff));
                const float v0 = __uint_as_float(p0.y);
                const float v1 = __uint_as_float(p1.y);
                const float v2 = __uint_as_float(p2.y);
                const float v3 = __uint_as_float(p3.y);
                a0 = fmaf(v0, __uint_as_float(g0 << 16), a0);
                a1 = fmaf(v0, __uint_as_float(g0 & 0xffff0000u), a1);
                a0 = fmaf(v1, __uint_as_float(g1 << 16), a0);
                a1 = fmaf(v1, __uint_as_float(g1 & 0xffff0000u), a1);
                a0 = fmaf(v2, __uint_as_float(g2 << 16), a0);
                a1 = fmaf(v2, __uint_as_float(g2 & 0xffff0000u), a1);
                a0 = fmaf(v3, __uint_as_float(g3 << 16), a0);
                a1 = fmaf(v3, __uint_as_float(g3 & 0xffff0000u), a1);
            }
            for (; i < end; i += 2) {
                const uint2 p = ebuf[i];
                const unsigned g = *((const unsigned*)(Zt + (size_t)p.x * COUT + choff));
                const float vp = __uint_as_float(p.y);
                a0 = fmaf(vp, __uint_as_float(g << 16), a0);
                a1 = fmaf(vp, __uint_as_float(g & 0xffff0000u), a1);
            }

            // combine the two edge-parity halves (lane <-> lane+32)
            a0 += __shfl_xor(a0, 32);
            a1 += __shfl_xor(a1, 32);

            if (eo == 0) {
                Zc[(size_t)row * (COUT / 2) + pass * 32 + cg] = pk2bf(a0, a1);
                s0 += a0; s1 += a1;
                q0 = fmaf(a0, a0, q0);
                q1 = fmaf(a1, a1, q1);
            }
        }

        if (eo == 0) {
            atomicAdd(&sbuf[choff + 0], s0);
            atomicAdd(&sbuf[choff + 1], s1);
            atomicAdd(&sbuf[128 + choff + 0], q0);
            atomicAdd(&sbuf[128 + choff + 1], q1);
        }
    }
    __syncthreads();
    atomicAdd(&stats[t], sbuf[t]);
}

// ---------------------------------------------------------------------------
// Kernel 3: BN(normalize) + ReLU + row-max -> out[N]  (bf16 Zc input)
// ---------------------------------------------------------------------------
__global__ __launch_bounds__(256) void finalize_kernel(
    const unsigned int* __restrict__ Zc, const float* __restrict__ stats,
    const float* __restrict__ gamma, const float* __restrict__ beta,
    float* __restrict__ out, int N)
{
    const int row = blockIdx.x * 4 + (threadIdx.x >> 6);
    if (row >= N) return;
    const int lane = threadIdx.x & 63;
    const int c0 = lane * 2;

    const unsigned g = Zc[(size_t)row * (COUT / 2) + lane];
    const float x0 = __uint_as_float(g << 16);
    const float x1 = __uint_as_float(g & 0xffff0000u);

    const float invN = 1.0f / (float)N;
    const float m0 = stats[c0] * invN;
    const float m1 = stats[c0 + 1] * invN;
    const float v0 = stats[128 + c0] * invN - m0 * m0;
    const float v1 = stats[128 + c0 + 1] * invN - m1 * m1;
    const float sc0 = gamma[c0]     * rsqrtf(v0 + BN_EPS);
    const float sc1 = gamma[c0 + 1] * rsqrtf(v1 + BN_EPS);

    float y0 = (x0 - m0) * sc0 + beta[c0];
    float y1 = (x1 - m1) * sc1 + beta[c0 + 1];
    y0 = fmaxf(y0, 0.f);
    y1 = fmaxf(y1, 0.f);

    float mx = fmaxf(y0, y1);
#pragma unroll
    for (int off = 32; off > 0; off >>= 1)
        mx = fmaxf(mx, __shfl_xor(mx, off));

    if (lane == 0) out[row] = mx;
}

// ---------------------------------------------------------------------------
extern "C" void kernel_launch(void* const* d_in, const int* in_sizes, int n_in,
                              void* d_out, int out_size, void* d_ws, size_t ws_size,
                              hipStream_t stream)
{
    const float* Z_H   = (const float*)d_in[0];
    const float* vals  = (const float*)d_in[1];
    const float* W     = (const float*)d_in[2];
    const float* b     = (const float*)d_in[3];
    const float* gamma = (const float*)d_in[4];
    const float* beta  = (const float*)d_in[5];
    const int*   rows  = (const int*)d_in[6];
    const int*   cols  = (const int*)d_in[7];
    float* out = (float*)d_out;

    const int N   = in_sizes[0] / CIN;
    const int nnz = in_sizes[1];
    const int NB  = (N + RPB - 1) / RPB;
    const int pblocks = (nnz + PCHUNK - 1) / PCHUNK;
    const int ntiles  = (N + 63) / 64;
    const int gb      = (ntiles + 2) / 3;    // exactly 3 tiles per gemm block

    // workspace layout (bucketCur and stats adjacent -> single memset)
    char* ws = (char*)d_ws;
    size_t off = 0;
    unsigned short* Zt = (unsigned short*)(ws + off); off += (size_t)N * COUT * sizeof(unsigned short);
    unsigned int*   Zc = (unsigned int*)(ws + off);   off += (size_t)N * (COUT / 2) * sizeof(unsigned int);
    uint2* ebuck  = (uint2*)(ws + off);  off += (size_t)NB * CAP * sizeof(uint2);
    int* bucketCur = (int*)(ws + off);   off += (size_t)NB * sizeof(int);
    float* stats   = (float*)(ws + off); off += 256 * sizeof(float);

    hipMemsetAsync(bucketCur, 0, ((size_t)NB + 256) * sizeof(int), stream);

    // 1) fused: bucket partition (first) || persistent MFMA GEMM
    gemm_part_kernel<<<pblocks + gb, 256, 0, stream>>>(
        Z_H, W, b, Zt, rows, cols, vals, bucketCur, ebuck, nnz, N, NB, pblocks, gb);

    // 2) fused per-bucket sort + channel-split two-pass gather + BN stats
    gather_build_kernel<<<NB, 256, 0, stream>>>(Zt, ebuck, bucketCur, Zc, stats, N);

    // 3) BN + ReLU + rowmax
    finalize_kernel<<<(N + 3) / 4, 256, 0, stream>>>(Zc, stats, gamma, beta, out, N);
}

// Round 17
// 229.391 us; speedup vs baseline: 1.0767x; 1.0146x over previous
//
#include <hip/hip_runtime.h>
#include <hip/hip_bf16.h>

#define CIN  128
#define COUT 128
#define BN_EPS 1e-5f
#define RPB   64           // rows per bucket (power of 2)
#define MAXNB 2048         // max buckets (N <= 131072)
#define PCHUNK 8192        // edges per partition block
#define CAP   2560         // padded capacity per bucket (mean 2046 + 11 sigma)
#define LDP   136          // padded LDS row stride (shorts): 272B, 16B-divisible
#define SMEM_BYTES 50176   // union: gemm (32768 W + 17408 cls) | partition (16KB)

typedef __attribute__((ext_vector_type(8))) short short8;
typedef __attribute__((ext_vector_type(4))) float f32x4;

// packed f32x2 -> bf16x2 bits (compiler lowers to v_cvt_pk_bf16_f32)
__device__ __forceinline__ unsigned pk2bf(float lo, float hi) {
    union { __hip_bfloat162 h; unsigned u; } c;
    c.h = __float22bfloat162_rn(make_float2(lo, hi));
    return c.u;
}

// ---------------------------------------------------------------------------
// GEMM body: Z_theta[N,128] = Z_H[N,128] @ W[128,128] + b  (bf16 out, MFMA)
// W staged ONCE per block into frag-ordered LDS (32 KB); fragments consumed
// as contiguous ds_read_b128 (lane l -> base + l*16B, full-BW pattern).
// Frees ~128 VGPRs -> 3 blocks/CU (12 waves) for latency hiding.
// Fragment layout (16x16x32): A/B lane l: m|n = l&15, k = (l>>4)*8 + e.
// C/D (verified): col = l&15, row = (l>>4)*4 + reg.
// ---------------------------------------------------------------------------
__device__ __forceinline__ void gemm_body(
    const float* __restrict__ Z, const float* __restrict__ W,
    const float* __restrict__ b, unsigned short* __restrict__ Zt,
    int N, int bid, int gb, char* smem)
{
    unsigned*       Wlds = (unsigned*)smem;                    // 8192 u32 = 32 KB
    unsigned short* cls  = (unsigned short*)(smem + 32768);    // 64*LDP shorts

    const int t    = threadIdx.x;
    const int lane = t & 63;
    const int wid  = t >> 6;
    const int lm   = lane & 15;
    const int lg   = lane >> 4;

    // stage W -> frag-ordered LDS: u32[((kc*8+ct)*64 + lg*16+lm)*4 + e/2]
#pragma unroll
    for (int j = 0; j < 32; ++j) {
        const int i  = j * 256 + t;
        const int k2 = i >> 7;            // even-k pair index 0..63
        const int c  = i & 127;
        const float w0 = W[(k2 * 2)     * COUT + c];
        const float w1 = W[(k2 * 2 + 1) * COUT + c];
        const int k  = k2 * 2;
        const int kc = k >> 5;
        const int lgs = (k >> 3) & 3;
        const int s  = (k & 7) >> 1;
        Wlds[(((kc * 8 + (c >> 4)) * 64) + lgs * 16 + (c & 15)) * 4 + s] = pk2bf(w0, w1);
    }

    float bias[8];
#pragma unroll
    for (int ct = 0; ct < 8; ++ct) bias[ct] = b[ct * 16 + lm];
    __syncthreads();

    const int tr = t >> 4;      // epilogue row 0..15
    const int cc = t & 15;      // epilogue 8-short chunk 0..15

    const int ntiles = (N + 63) / 64;
    for (int tile = bid; tile < ntiles; tile += gb) {
        const int row0 = tile * 64 + wid * 16;
        const int arow = row0 + lm;
        const bool aval = arow < N;
        const float* zrow = Z + (size_t)arow * CIN;

        f32x4 acc[8];
#pragma unroll
        for (int ct = 0; ct < 8; ++ct) {
            f32x4 a = {bias[ct], bias[ct], bias[ct], bias[ct]};
            acc[ct] = a;
        }

#pragma unroll
        for (int kc = 0; kc < 4; ++kc) {
            union { short8 v; unsigned u32[4]; } af;
            if (aval) {
                const float4 z0 = *((const float4*)(zrow + kc * 32 + lg * 8));
                const float4 z1 = *((const float4*)(zrow + kc * 32 + lg * 8 + 4));
                af.u32[0] = pk2bf(z0.x, z0.y);
                af.u32[1] = pk2bf(z0.z, z0.w);
                af.u32[2] = pk2bf(z1.x, z1.y);
                af.u32[3] = pk2bf(z1.z, z1.w);
            } else {
#pragma unroll
                for (int e = 0; e < 4; ++e) af.u32[e] = 0;
            }
#pragma unroll
            for (int ct = 0; ct < 8; ++ct) {
                const short8 bf = *((const short8*)(Wlds + ((kc * 8 + ct) * 64 + lane) * 4));
                acc[ct] = __builtin_amdgcn_mfma_f32_16x16x32_bf16(af.v, bf, acc[ct], 0, 0, 0);
            }
        }

        // epilogue: acc -> LDS (packed converts) -> coalesced 16B stores
        __syncthreads();   // previous tile's LDS readers done
#pragma unroll
        for (int i = 0; i < 4; ++i) {
            const int r = wid * 16 + lg * 4 + i;
#pragma unroll
            for (int ct = 0; ct < 8; ct += 2) {
                const unsigned u = pk2bf(acc[ct][i], acc[ct + 1][i]);
                cls[r * LDP + ct * 16 + lm]       = (unsigned short)(u & 0xffffu);
                cls[r * LDP + (ct + 1) * 16 + lm] = (unsigned short)(u >> 16);
            }
        }
        __syncthreads();

#pragma unroll
        for (int j = 0; j < 4; ++j) {
            const int r = j * 16 + tr;
            const int grow = tile * 64 + r;
            if (grow < N) {
                const uint4 v = *((const uint4*)&cls[r * LDP + cc * 8]);
                *((uint4*)(Zt + (size_t)grow * COUT + cc * 8)) = v;
            }
        }
    }
}

// ---------------------------------------------------------------------------
// Partition body: bucket edges into PADDED per-bucket regions.
// bucketCur holds RELATIVE offsets (zero-init); absolute = b*CAP + rel.
// Payload: col (17b) | row-local (6b) << 17, val.
// ---------------------------------------------------------------------------
__device__ __forceinline__ void partition_body(
    const int* __restrict__ rows, const int* __restrict__ cols,
    const float* __restrict__ vals, int* __restrict__ bucketCur,
    uint2* __restrict__ ebuck, int nnz, int NB, int pb, char* smem)
{
    int* h       = (int*)smem;           // MAXNB ints
    int* basecur = h + MAXNB;            // MAXNB ints (16 KB total)
    const int t = threadIdx.x;

    for (int i = t; i < NB; i += 256) h[i] = 0;
    __syncthreads();

    const int c0 = pb * PCHUNK;
    const int ce = min(c0 + PCHUNK, nnz);

    int rloc[PCHUNK / 256];
#pragma unroll
    for (int j = 0; j < PCHUNK / 256; ++j) {
        const int i = c0 + j * 256 + t;
        int r = -1;
        if (i < ce) r = rows[i];
        rloc[j] = r;
        if (r >= 0) atomicAdd(&h[r >> 6], 1);
    }
    __syncthreads();

    for (int i = t; i < NB; i += 256) {
        const int c = h[i];
        basecur[i] = c ? (i * CAP + atomicAdd(&bucketCur[i], c)) : 0;
    }
    __syncthreads();

#pragma unroll
    for (int j = 0; j < PCHUNK / 256; ++j) {
        const int i = c0 + j * 256 + t;
        const int r = rloc[j];
        if (r >= 0) {
            const int p = atomicAdd(&basecur[r >> 6], 1);
            ebuck[p] = make_uint2((unsigned)cols[i] | ((unsigned)(r & (RPB - 1)) << 17),
                                  __float_as_uint(vals[i]));
        }
    }
}

// ---------------------------------------------------------------------------
// Kernel 1: fused partition (blocks 0..pblocks-1) || GEMM (rest).
// Explicit shared-memory union keeps LDS at 50176 B -> 3 blocks/CU.
// ---------------------------------------------------------------------------
__global__ __launch_bounds__(256, 3) void gemm_part_kernel(
    const float* __restrict__ Z, const float* __restrict__ W,
    const float* __restrict__ b, unsigned short* __restrict__ Zt,
    const int* __restrict__ rows, const int* __restrict__ cols,
    const float* __restrict__ vals, int* __restrict__ bucketCur,
    uint2* __restrict__ ebuck, int nnz, int N, int NB, int pblocks, int gb)
{
    __shared__ char smem[SMEM_BYTES];
    if ((int)blockIdx.x < pblocks) {
        partition_body(rows, cols, vals, bucketCur, ebuck, nnz, NB, blockIdx.x, smem);
    } else {
        gemm_body(Z, W, b, Zt, N, blockIdx.x - pblocks, gb, smem);
    }
}

// ---------------------------------------------------------------------------
// Kernel 2: fused per-bucket row-sort (in LDS) + CHANNEL-SPLIT two-pass
// per-row gather + BN stats. Pass p covers channels [p*64, p*64+64).
// ---------------------------------------------------------------------------
__global__ __launch_bounds__(256) void gather_build_kernel(
    const unsigned short* __restrict__ Zt, const uint2* __restrict__ ebuck,
    const int* __restrict__ bucketCur, unsigned int* __restrict__ Zc,
    float* __restrict__ stats, int N)
{
    __shared__ int cnt[RPB];
    __shared__ int scn[RPB];
    __shared__ int loc[RPB];
    __shared__ uint2 ebuf[CAP];        // 20 KB sorted edges
    __shared__ float sbuf[256];

    const int t = threadIdx.x;
    const int b = blockIdx.x;
    const int base = b * CAP;
    int count = bucketCur[b];
    if (count > CAP) count = CAP;

    sbuf[t] = 0.f;
    if (t < RPB) cnt[t] = 0;
    __syncthreads();

    uint2 er[CAP / 256];
#pragma unroll
    for (int j = 0; j < CAP / 256; ++j) {
        const int i = j * 256 + t;
        if (i < count) {
            er[j] = ebuck[base + i];
            atomicAdd(&cnt[er[j].x >> 17], 1);
        }
    }
    __syncthreads();

    if (t < RPB) scn[t] = cnt[t];
    __syncthreads();
#pragma unroll
    for (int off = 1; off < RPB; off <<= 1) {
        int v = 0;
        if (t < RPB && t >= off) v = scn[t - off];
        __syncthreads();
        if (t < RPB) scn[t] += v;
        __syncthreads();
    }
    if (t < RPB) loc[t] = scn[t] - cnt[t];
    __syncthreads();

#pragma unroll
    for (int j = 0; j < CAP / 256; ++j) {
        const int i = j * 256 + t;
        if (i < count) {
            const uint2 e = er[j];
            const int rl  = (int)(e.x >> 17);
            const int pos = atomicAdd(&loc[rl], 1);
            ebuf[pos] = make_uint2(e.x & 0x1FFFFu, e.y);
        }
    }
    __syncthreads();

    const int wid  = t >> 6;
    const int lane = t & 63;
    const int eo   = lane >> 5;
    const int cg   = lane & 31;

    const int row0 = b * RPB;

#pragma unroll
    for (int pass = 0; pass < 2; ++pass) {
        const int choff = pass * 64 + cg * 2;   // this lane's channel pair

        float s0 = 0.f, s1 = 0.f, q0 = 0.f, q1 = 0.f;

        for (int r = wid; r < RPB; r += 4) {
            const int row = row0 + r;
            if (row >= N) break;
            const int end = scn[r];
            const int beg = end - cnt[r];

            float a0 = 0.f, a1 = 0.f;

            int i = beg + eo;
            for (; i + 6 < end; i += 8) {
                const uint2 p0 = ebuf[i];
                const uint2 p1 = ebuf[i + 2];
                const uint2 p2 = ebuf[i + 4];
                const uint2 p3 = ebuf[i + 6];
                const unsigned g0 = *((const unsigned*)(Zt + (size_t)p0.x * COUT + choff));
                const unsigned g1 = *((const unsigned*)(Zt + (size_t)p1.x * COUT + choff));
                const unsigned g2 = *((const unsigned*)(Zt + (size_t)p2.x * COUT + choff));
                const unsigned g3 = *((const unsigned*)(Zt + (size_t)p3.x * COUT + choff));
                const float v0 = __uint_as_float(p0.y);
                const float v1 = __uint_as_float(p1.y);
                const float v2 = __uint_as_float(p2.y);
                const float v3 = __uint_as_float(p3.y);
                a0 = fmaf(v0, __uint_as_float(g0 << 16), a0);
                a1 = fmaf(v0, __uint_as_float(g0 & 0xffff0000u), a1);
                a0 = fmaf(v1, __uint_as_float(g1 << 16), a0);
                a1 = fmaf(v1, __uint_as_float(g1 & 0xffff0000u), a1);
                a0 = fmaf(v2, __uint_as_float(g2 << 16), a0);
                a1 = fmaf(v2, __uint_as_float(g2 & 0xffff0000u), a1);
                a0 = fmaf(v3, __uint_as_float(g3 << 16), a0);
                a1 = fmaf(v3, __uint_as_float(g3 & 0xffff0000u), a1);
            }
            for (; i < end; i += 2) {
                const uint2 p = ebuf[i];
                const unsigned g = *((const unsigned*)(Zt + (size_t)p.x * COUT + choff));
                const float vp = __uint_as_float(p.y);
                a0 = fmaf(vp, __uint_as_float(g << 16), a0);
                a1 = fmaf(vp, __uint_as_float(g & 0xffff0000u), a1);
            }

            a0 += __shfl_xor(a0, 32);
            a1 += __shfl_xor(a1, 32);

            if (eo == 0) {
                Zc[(size_t)row * (COUT / 2) + pass * 32 + cg] = pk2bf(a0, a1);
                s0 += a0; s1 += a1;
                q0 = fmaf(a0, a0, q0);
                q1 = fmaf(a1, a1, q1);
            }
        }

        if (eo == 0) {
            atomicAdd(&sbuf[choff + 0], s0);
            atomicAdd(&sbuf[choff + 1], s1);
            atomicAdd(&sbuf[128 + choff + 0], q0);
            atomicAdd(&sbuf[128 + choff + 1], q1);
        }
    }
    __syncthreads();
    atomicAdd(&stats[t], sbuf[t]);
}

// ---------------------------------------------------------------------------
// Kernel 3: BN(normalize) + ReLU + row-max -> out[N]  (bf16 Zc input)
// ---------------------------------------------------------------------------
__global__ __launch_bounds__(256) void finalize_kernel(
    const unsigned int* __restrict__ Zc, const float* __restrict__ stats,
    const float* __restrict__ gamma, const float* __restrict__ beta,
    float* __restrict__ out, int N)
{
    const int row = blockIdx.x * 4 + (threadIdx.x >> 6);
    if (row >= N) return;
    const int lane = threadIdx.x & 63;
    const int c0 = lane * 2;

    const unsigned g = Zc[(size_t)row * (COUT / 2) + lane];
    const float x0 = __uint_as_float(g << 16);
    const float x1 = __uint_as_float(g & 0xffff0000u);

    const float invN = 1.0f / (float)N;
    const float m0 = stats[c0] * invN;
    const float m1 = stats[c0 + 1] * invN;
    const float v0 = stats[128 + c0] * invN - m0 * m0;
    const float v1 = stats[128 + c0 + 1] * invN - m1 * m1;
    const float sc0 = gamma[c0]     * rsqrtf(v0 + BN_EPS);
    const float sc1 = gamma[c0 + 1] * rsqrtf(v1 + BN_EPS);

    float y0 = (x0 - m0) * sc0 + beta[c0];
    float y1 = (x1 - m1) * sc1 + beta[c0 + 1];
    y0 = fmaxf(y0, 0.f);
    y1 = fmaxf(y1, 0.f);

    float mx = fmaxf(y0, y1);
#pragma unroll
    for (int off = 32; off > 0; off >>= 1)
        mx = fmaxf(mx, __shfl_xor(mx, off));

    if (lane == 0) out[row] = mx;
}

// ---------------------------------------------------------------------------
extern "C" void kernel_launch(void* const* d_in, const int* in_sizes, int n_in,
                              void* d_out, int out_size, void* d_ws, size_t ws_size,
                              hipStream_t stream)
{
    const float* Z_H   = (const float*)d_in[0];
    const float* vals  = (const float*)d_in[1];
    const float* W     = (const float*)d_in[2];
    const float* b     = (const float*)d_in[3];
    const float* gamma = (const float*)d_in[4];
    const float* beta  = (const float*)d_in[5];
    const int*   rows  = (const int*)d_in[6];
    const int*   cols  = (const int*)d_in[7];
    float* out = (float*)d_out;

    const int N   = in_sizes[0] / CIN;
    const int nnz = in_sizes[1];
    const int NB  = (N + RPB - 1) / RPB;
    const int pblocks = (nnz + PCHUNK - 1) / PCHUNK;
    const int ntiles  = (N + 63) / 64;
    const int gb      = (ntiles + 3) / 4;    // exactly 4 tiles per gemm block

    // workspace layout (bucketCur and stats adjacent -> single memset)
    char* ws = (char*)d_ws;
    size_t off = 0;
    unsigned short* Zt = (unsigned short*)(ws + off); off += (size_t)N * COUT * sizeof(unsigned short);
    unsigned int*   Zc = (unsigned int*)(ws + off);   off += (size_t)N * (COUT / 2) * sizeof(unsigned int);
    uint2* ebuck  = (uint2*)(ws + off);  off += (size_t)NB * CAP * sizeof(uint2);
    int* bucketCur = (int*)(ws + off);   off += (size_t)NB * sizeof(int);
    float* stats   = (float*)(ws + off); off += 256 * sizeof(float);

    hipMemsetAsync(bucketCur, 0, ((size_t)NB + 256) * sizeof(int), stream);

    // 1) fused: bucket partition (first) || persistent MFMA GEMM (W in LDS)
    gemm_part_kernel<<<pblocks + gb, 256, 0, stream>>>(
        Z_H, W, b, Zt, rows, cols, vals, bucketCur, ebuck, nnz, N, NB, pblocks, gb);

    // 2) fused per-bucket sort + channel-split two-pass gather + BN stats
    gather_build_kernel<<<NB, 256, 0, stream>>>(Zt, ebuck, bucketCur, Zc, stats, N);

    // 3) BN + ReLU + rowmax
    finalize_kernel<<<(N + 3) / 4, 256, 0, stream>>>(Zc, stats, gamma, beta, out, N);
}